// Round 3
// baseline (2179.789 us; speedup 1.0000x reference)
//
#include <hip/hip_runtime.h>

#define FDIM 16

typedef float f32x4 __attribute__((ext_vector_type(4)));  // native vec for nontemporal store

struct PlanePtrs { const float* p[12]; };

// PAIRS = (0,1),(0,2),(1,2),(0,3),(1,3),(2,3)
// i-selectors packed: 0,0,1,0,1,2 -> 2320 ; j-selectors: 1,2,2,3,3,3 -> 4073
__device__ __forceinline__ void plane_dims(int k, int& H, int& W, int& toff,
                                           int& isel, int& jsel) {
    int pi  = (k >= 6) ? (k - 6) : k;
    int lvl = (k >= 6) ? 1 : 0;
    isel = (2320 >> (2 * pi)) & 3;
    jsel = (4073 >> (2 * pi)) & 3;
    // plane shape is (F, res[i], res[j]); gy=c[j] indexes H=res[i], gx=c[i] indexes W=res[j]
    H = ((isel == 3) ? 150 : 128) >> lvl;
    W = ((jsel == 3) ? 150 : 128) >> lvl;
    // cumulative texel offsets: 3x16384, 3x19200, 3x4096, 3x4800
    if (k < 6) {
        toff = (k < 3) ? k * 16384 : 49152 + (k - 3) * 19200;
    } else {
        int kk = k - 6;
        toff = 106752 + ((kk < 3) ? kk * 4096 : 12288 + (kk - 3) * 4800);
    }
}

// (F,H,W) -> (H,W,F) so the 16 features of a texel are contiguous (4 x float4)
__global__ void __launch_bounds__(256) hex_transpose(PlanePtrs ptrs,
                                                     float4* __restrict__ ws4) {
    int k = blockIdx.y;
    int H, W, toff, isel, jsel;
    plane_dims(k, H, W, toff, isel, jsel);
    int HW = H * W;
    int t = blockIdx.x * 256 + threadIdx.x;
    if (t >= HW) return;
    const float* __restrict__ src = ptrs.p[k];
    float v[FDIM];
#pragma unroll
    for (int f = 0; f < FDIM; ++f) v[f] = src[f * HW + t];   // coalesced per f
    float4* dst = ws4 + (size_t)(toff + t) * 4;
#pragma unroll
    for (int j = 0; j < 4; ++j)
        dst[j] = make_float4(v[4 * j], v[4 * j + 1], v[4 * j + 2], v[4 * j + 3]);
}

// One thread = one (point, plane): all 16 features. blockIdx.y = plane k, so
// plane params are wave-uniform and a wave's gathers hit ONE plane (<=1.2 MB,
// L2-resident). coords load is perfectly coalesced. Output stored nontemporal
// (streaming; keep L2 for planes) as 4 consecutive float4 = one 64B sector.
__global__ void __launch_bounds__(256) hex_sample(const float4* __restrict__ coords,
                                                  const float4* __restrict__ ws4,
                                                  f32x4* __restrict__ out4,
                                                  int points) {
    int p = blockIdx.x * 256 + threadIdx.x;
    if (p >= points) return;
    int k = blockIdx.y;                 // uniform across block

    int H, W, toff, isel, jsel;
    plane_dims(k, H, W, toff, isel, jsel);   // all SGPR math (k uniform)

    float4 c = coords[p];               // lane-stride 16B: perfectly coalesced

    // isel in {0,1,2}, jsel in {1,2,3}
    float gx = (isel == 0) ? c.x : (isel == 1) ? c.y : c.z;
    float gy = (jsel == 1) ? c.y : (jsel == 2) ? c.z : c.w;

    // align_corners=True + border padding: clip BEFORE floor
    float fx = (gx + 1.0f) * 0.5f * (float)(W - 1);
    fx = fminf(fmaxf(fx, 0.0f), (float)(W - 1));
    float fy = (gy + 1.0f) * 0.5f * (float)(H - 1);
    fy = fminf(fmaxf(fy, 0.0f), (float)(H - 1));

    float x0f = floorf(fx), y0f = floorf(fy);
    int x0 = (int)x0f, y0 = (int)y0f;
    int x1 = min(x0 + 1, W - 1);
    int y1 = min(y0 + 1, H - 1);
    float wx = fx - x0f, wy = fy - y0f;

    const float4* __restrict__ base = ws4 + (size_t)toff * 4;
    int i00 = (y0 * W + x0) * 4;
    int i01 = (y0 * W + x1) * 4;
    int i10 = (y1 * W + x0) * 4;
    int i11 = (y1 * W + x1) * 4;

    f32x4* o = out4 + ((size_t)p * 12 + k) * 4;

#pragma unroll
    for (int q = 0; q < 4; ++q) {
        float4 v00 = base[i00 + q];
        float4 v01 = base[i01 + q];
        float4 v10 = base[i10 + q];
        float4 v11 = base[i11 + q];
        // bilinear as two lerps per component: v0 + (v1-v0)*w
        float4 t0, t1;
        t0.x = v00.x + (v01.x - v00.x) * wx;
        t0.y = v00.y + (v01.y - v00.y) * wx;
        t0.z = v00.z + (v01.z - v00.z) * wx;
        t0.w = v00.w + (v01.w - v00.w) * wx;
        t1.x = v10.x + (v11.x - v10.x) * wx;
        t1.y = v10.y + (v11.y - v10.y) * wx;
        t1.z = v10.z + (v11.z - v10.z) * wx;
        t1.w = v10.w + (v11.w - v10.w) * wx;
        f32x4 r;
        r.x = t0.x + (t1.x - t0.x) * wy;
        r.y = t0.y + (t1.y - t0.y) * wy;
        r.z = t0.z + (t1.z - t0.z) * wy;
        r.w = t0.w + (t1.w - t0.w) * wy;
        __builtin_nontemporal_store(r, o + q);
    }
}

extern "C" void kernel_launch(void* const* d_in, const int* in_sizes, int n_in,
                              void* d_out, int out_size, void* d_ws, size_t ws_size,
                              hipStream_t stream) {
    const float4* coords = (const float4*)d_in[0];
    PlanePtrs pp;
    for (int i = 0; i < 12; ++i) pp.p[i] = (const float*)d_in[1 + i];
    float4* ws4  = (float4*)d_ws;    // needs 8,540,160 bytes
    f32x4* out4  = (f32x4*)d_out;

    int points = in_sizes[0] / 4;    // 800,000

    // transpose: max HW = 19200 -> 75 blocks; y = plane index
    dim3 tgrid(75, 12);
    hex_transpose<<<tgrid, 256, 0, stream>>>(pp, ws4);

    // sample: x over point chunks, y over the 12 planes
    dim3 sgrid((points + 255) / 256, 12);
    hex_sample<<<sgrid, 256, 0, stream>>>(coords, ws4, out4, points);
}

// Round 4
// 1112.513 us; speedup vs baseline: 1.9593x; 1.9593x over previous
//
#include <hip/hip_runtime.h>

#define FDIM 16

struct PlanePtrs { const float* p[12]; };

// PAIRS = (0,1),(0,2),(1,2),(0,3),(1,3),(2,3)
// i-selectors packed: 0,0,1,0,1,2 -> 2320 ; j-selectors: 1,2,2,3,3,3 -> 4073
__device__ __forceinline__ void plane_dims(int k, int& H, int& W, int& toff,
                                           int& isel, int& jsel) {
    int pi  = (k >= 6) ? (k - 6) : k;
    int lvl = (k >= 6) ? 1 : 0;
    isel = (2320 >> (2 * pi)) & 3;
    jsel = (4073 >> (2 * pi)) & 3;
    // plane shape is (F, res[i], res[j]); gy=c[j] indexes H=res[i], gx=c[i] indexes W=res[j]
    H = ((isel == 3) ? 150 : 128) >> lvl;
    W = ((jsel == 3) ? 150 : 128) >> lvl;
    // cumulative texel offsets: 3x16384, 3x19200, 3x4096, 3x4800
    if (k < 6) {
        toff = (k < 3) ? k * 16384 : 49152 + (k - 3) * 19200;
    } else {
        int kk = k - 6;
        toff = 106752 + ((kk < 3) ? kk * 4096 : 12288 + (kk - 3) * 4800);
    }
}

// (F,H,W) -> (H,W,F) so the 16 features of a texel are contiguous (4 x float4)
__global__ void __launch_bounds__(256) hex_transpose(PlanePtrs ptrs,
                                                     float4* __restrict__ ws4) {
    int k = blockIdx.y;
    int H, W, toff, isel, jsel;
    plane_dims(k, H, W, toff, isel, jsel);
    int HW = H * W;
    int t = blockIdx.x * 256 + threadIdx.x;
    if (t >= HW) return;
    const float* __restrict__ src = ptrs.p[k];
    float v[FDIM];
#pragma unroll
    for (int f = 0; f < FDIM; ++f) v[f] = src[f * HW + t];   // coalesced per f
    float4* dst = ws4 + (size_t)(toff + t) * 4;
#pragma unroll
    for (int j = 0; j < 4; ++j)
        dst[j] = make_float4(v[4 * j], v[4 * j + 1], v[4 * j + 2], v[4 * j + 3]);
}

// One thread = one (point, plane), all 16 features. Block = 768 threads =
// 64 points x 12 planes, so thread t's 64B output chunk sits at
// block_base + t*64: the block writes one contiguous 48 KB region and L2
// write-back merges the 4x16B stores per lane into full-sector HBM bursts.
// (Round-3 lesson: nontemporal 16B stores at 768B lane stride = 2.7x write
// amplification. Normal cached stores + lane-contiguous layout fix it.)
__global__ void __launch_bounds__(768) hex_sample(const float4* __restrict__ coords,
                                                  const float4* __restrict__ ws4,
                                                  float4* __restrict__ out4,
                                                  int points) {
    int t = threadIdx.x;
    int p_local = t / 12;               // 0..63
    int k = t - p_local * 12;           // 0..11
    int p = blockIdx.x * 64 + p_local;
    if (p >= points) return;

    int H, W, toff, isel, jsel;
    plane_dims(k, H, W, toff, isel, jsel);

    float4 c = coords[p];               // 12 lanes share a line: L1 broadcast

    // isel in {0,1,2}, jsel in {1,2,3}
    float gx = (isel == 0) ? c.x : (isel == 1) ? c.y : c.z;
    float gy = (jsel == 1) ? c.y : (jsel == 2) ? c.z : c.w;

    // align_corners=True + border padding: clip BEFORE floor
    float fx = (gx + 1.0f) * 0.5f * (float)(W - 1);
    fx = fminf(fmaxf(fx, 0.0f), (float)(W - 1));
    float fy = (gy + 1.0f) * 0.5f * (float)(H - 1);
    fy = fminf(fmaxf(fy, 0.0f), (float)(H - 1));

    float x0f = floorf(fx), y0f = floorf(fy);
    int x0 = (int)x0f, y0 = (int)y0f;
    int x1 = min(x0 + 1, W - 1);
    int y1 = min(y0 + 1, H - 1);
    float wx = fx - x0f, wy = fy - y0f;

    const float4* __restrict__ base = ws4 + (size_t)toff * 4;
    int i00 = (y0 * W + x0) * 4;
    int i01 = (y0 * W + x1) * 4;
    int i10 = (y1 * W + x0) * 4;
    int i11 = (y1 * W + x1) * 4;

    float4* o = out4 + ((size_t)p * 12 + k) * 4;   // == block_base + t*4 float4s

#pragma unroll
    for (int q = 0; q < 4; ++q) {
        float4 v00 = base[i00 + q];
        float4 v01 = base[i01 + q];
        float4 v10 = base[i10 + q];
        float4 v11 = base[i11 + q];
        // bilinear as two lerps per component: v0 + (v1-v0)*w
        float4 t0, t1, r;
        t0.x = v00.x + (v01.x - v00.x) * wx;
        t0.y = v00.y + (v01.y - v00.y) * wx;
        t0.z = v00.z + (v01.z - v00.z) * wx;
        t0.w = v00.w + (v01.w - v00.w) * wx;
        t1.x = v10.x + (v11.x - v10.x) * wx;
        t1.y = v10.y + (v11.y - v10.y) * wx;
        t1.z = v10.z + (v11.z - v10.z) * wx;
        t1.w = v10.w + (v11.w - v10.w) * wx;
        r.x = t0.x + (t1.x - t0.x) * wy;
        r.y = t0.y + (t1.y - t0.y) * wy;
        r.z = t0.z + (t1.z - t0.z) * wy;
        r.w = t0.w + (t1.w - t0.w) * wy;
        o[q] = r;
    }
}

extern "C" void kernel_launch(void* const* d_in, const int* in_sizes, int n_in,
                              void* d_out, int out_size, void* d_ws, size_t ws_size,
                              hipStream_t stream) {
    const float4* coords = (const float4*)d_in[0];
    PlanePtrs pp;
    for (int i = 0; i < 12; ++i) pp.p[i] = (const float*)d_in[1 + i];
    float4* ws4  = (float4*)d_ws;    // needs 8,540,160 bytes
    float4* out4 = (float4*)d_out;

    int points = in_sizes[0] / 4;    // 800,000

    // transpose: max HW = 19200 -> 75 blocks; y = plane index
    dim3 tgrid(75, 12);
    hex_transpose<<<tgrid, 256, 0, stream>>>(pp, ws4);

    // sample: 64 points x 12 planes per 768-thread block
    int blocks = (points + 63) / 64;
    hex_sample<<<blocks, 768, 0, stream>>>(coords, ws4, out4, points);
}

// Round 10
// 1038.981 us; speedup vs baseline: 2.0980x; 1.0708x over previous
//
#include <hip/hip_runtime.h>

#define FDIM 16

struct PlanePtrs { const float* p[12]; };

// PAIRS = (0,1),(0,2),(1,2),(0,3),(1,3),(2,3)
// i-selectors packed: 0,0,1,0,1,2 -> 2320 ; j-selectors: 1,2,2,3,3,3 -> 4073
__device__ __forceinline__ void plane_dims(int k, int& H, int& W, int& toff,
                                           int& isel, int& jsel) {
    int pi  = (k >= 6) ? (k - 6) : k;
    int lvl = (k >= 6) ? 1 : 0;
    isel = (2320 >> (2 * pi)) & 3;
    jsel = (4073 >> (2 * pi)) & 3;
    // plane shape is (F, res[i], res[j]); gy=c[j] indexes H=res[i], gx=c[i] indexes W=res[j]
    H = ((isel == 3) ? 150 : 128) >> lvl;
    W = ((jsel == 3) ? 150 : 128) >> lvl;
    // cumulative texel offsets: 3x16384, 3x19200, 3x4096, 3x4800
    if (k < 6) {
        toff = (k < 3) ? k * 16384 : 49152 + (k - 3) * 19200;
    } else {
        int kk = k - 6;
        toff = 106752 + ((kk < 3) ? kk * 4096 : 12288 + (kk - 3) * 4800);
    }
}

// (F,H,W) -> (H,W,F) so the 16 features of a texel are contiguous (4 x float4)
__global__ void __launch_bounds__(256) hex_transpose(PlanePtrs ptrs,
                                                     float4* __restrict__ ws4) {
    int k = blockIdx.y;
    int H, W, toff, isel, jsel;
    plane_dims(k, H, W, toff, isel, jsel);
    int HW = H * W;
    int t = blockIdx.x * 256 + threadIdx.x;
    if (t >= HW) return;
    const float* __restrict__ src = ptrs.p[k];
    float v[FDIM];
#pragma unroll
    for (int f = 0; f < FDIM; ++f) v[f] = src[f * HW + t];   // coalesced per f
    float4* dst = ws4 + (size_t)(toff + t) * 4;
#pragma unroll
    for (int j = 0; j < 4; ++j)
        dst[j] = make_float4(v[4 * j], v[4 * j + 1], v[4 * j + 2], v[4 * j + 3]);
}

// One thread = one POINT, unrolled loop over all 12 planes.
//  - plane params constant-fold per unrolled iteration (no divergent math)
//  - thread writes its full 768B output contiguously (block: 192KB contiguous)
//    -> keeps round-4's ideal WRITE_SIZE (~675MB)
//  - co-resident blocks iterate k in rough lockstep, so concurrent gathers
//    cluster on ONE ~1.2MB plane -> L2-resident per XCD (round-3's 108MB
//    FETCH behavior) without giving up store contiguity.
__global__ void __launch_bounds__(256) hex_sample(const float4* __restrict__ coords,
                                                  const float4* __restrict__ ws4,
                                                  float4* __restrict__ out4,
                                                  int points) {
    int p = blockIdx.x * 256 + threadIdx.x;
    if (p >= points) return;

    float4 c = coords[p];               // one coalesced 16B load per point
    float4* o = out4 + (size_t)p * 48;  // 768B contiguous per thread

#pragma unroll
    for (int k = 0; k < 12; ++k) {
        int H, W, toff, isel, jsel;
        plane_dims(k, H, W, toff, isel, jsel);   // all compile-time constants

        float gx = (isel == 0) ? c.x : (isel == 1) ? c.y : c.z;
        float gy = (jsel == 1) ? c.y : (jsel == 2) ? c.z : c.w;

        // align_corners=True + border padding: clip BEFORE floor
        float fx = (gx + 1.0f) * 0.5f * (float)(W - 1);
        fx = fminf(fmaxf(fx, 0.0f), (float)(W - 1));
        float fy = (gy + 1.0f) * 0.5f * (float)(H - 1);
        fy = fminf(fmaxf(fy, 0.0f), (float)(H - 1));

        float x0f = floorf(fx), y0f = floorf(fy);
        int x0 = (int)x0f, y0 = (int)y0f;
        int x1 = min(x0 + 1, W - 1);
        int y1 = min(y0 + 1, H - 1);
        float wx = fx - x0f, wy = fy - y0f;

        const float4* __restrict__ base = ws4 + (size_t)toff * 4;
        int i00 = (y0 * W + x0) * 4;
        int i01 = (y0 * W + x1) * 4;
        int i10 = (y1 * W + x0) * 4;
        int i11 = (y1 * W + x1) * 4;

#pragma unroll
        for (int q = 0; q < 4; ++q) {
            float4 v00 = base[i00 + q];
            float4 v01 = base[i01 + q];
            float4 v10 = base[i10 + q];
            float4 v11 = base[i11 + q];
            // bilinear as two lerps per component: v0 + (v1-v0)*w
            float4 t0, t1, r;
            t0.x = v00.x + (v01.x - v00.x) * wx;
            t0.y = v00.y + (v01.y - v00.y) * wx;
            t0.z = v00.z + (v01.z - v00.z) * wx;
            t0.w = v00.w + (v01.w - v00.w) * wx;
            t1.x = v10.x + (v11.x - v10.x) * wx;
            t1.y = v10.y + (v11.y - v10.y) * wx;
            t1.z = v10.z + (v11.z - v10.z) * wx;
            t1.w = v10.w + (v11.w - v10.w) * wx;
            r.x = t0.x + (t1.x - t0.x) * wy;
            r.y = t0.y + (t1.y - t0.y) * wy;
            r.z = t0.z + (t1.z - t0.z) * wy;
            r.w = t0.w + (t1.w - t0.w) * wy;
            o[k * 4 + q] = r;
        }
    }
}

extern "C" void kernel_launch(void* const* d_in, const int* in_sizes, int n_in,
                              void* d_out, int out_size, void* d_ws, size_t ws_size,
                              hipStream_t stream) {
    const float4* coords = (const float4*)d_in[0];
    PlanePtrs pp;
    for (int i = 0; i < 12; ++i) pp.p[i] = (const float*)d_in[1 + i];
    float4* ws4  = (float4*)d_ws;    // needs 8,540,160 bytes
    float4* out4 = (float4*)d_out;

    int points = in_sizes[0] / 4;    // 800,000

    // transpose: max HW = 19200 -> 75 blocks; y = plane index
    dim3 tgrid(75, 12);
    hex_transpose<<<tgrid, 256, 0, stream>>>(pp, ws4);

    // sample: one thread per point
    int blocks = (points + 255) / 256;
    hex_sample<<<blocks, 256, 0, stream>>>(coords, ws4, out4, points);
}